// Round 2
// baseline (2623.544 us; speedup 1.0000x reference)
//
#include <hip/hip_runtime.h>

#define N_NODES 50000
#define N_EDGES 100000
#define DD 32
#define STEPS 5

// prop[n, j] = emb[token[n], j]
__global__ void init_prop(const int* __restrict__ token,
                          const float* __restrict__ emb,
                          float* __restrict__ prop) {
    int idx = blockIdx.x * 256 + threadIdx.x;   // over N*D = 1.6M, exact grid
    int n = idx >> 5, j = idx & 31;
    prop[idx] = emb[token[n] * DD + j];
}

// One half-wave (32 lanes) per edge. Lane j computes output column j for both
// fwd (k=0) and rev (k=1) transforms:
//   fea[e,j,k] = sum_i prop[src[e],i] * W_edge[etype[e],i,j,k]
// then scatter-adds: in_fea[dst[e],j] += fea[...,0]; out_fea[src[e],j] += fea[...,1]
__global__ void edge_kernel(const int* __restrict__ etype,
                            const int* __restrict__ src,
                            const int* __restrict__ dst,
                            const float* __restrict__ W_edge,
                            const float* __restrict__ prop,
                            float* __restrict__ in_fea,
                            float* __restrict__ out_fea) {
    int e = blockIdx.x * 8 + (threadIdx.x >> 5);   // 12500 * 8 = 100000 exact
    int lane = threadIdx.x & 63;
    int j = threadIdx.x & 31;
    int base = lane & 32;                          // this half-wave's lane origin
    int s = src[e], d = dst[e], t = etype[e];
    float h = prop[s * DD + j];                    // lane j holds h_src[j]
    // W_edge[t,i,j,k]: k=0/1 contiguous -> float2 at pair index t*1024 + i*32 + j
    const float2* W2 = (const float2*)W_edge + (size_t)t * (DD * DD);
    float accF = 0.f, accR = 0.f;
#pragma unroll
    for (int i = 0; i < DD; ++i) {
        float hi = __shfl(h, base + i);            // broadcast h_src[i] within half-wave
        float2 w = W2[i * DD + j];                 // coalesced over j, L1/L2-resident
        accF += hi * w.x;
        accR += hi * w.y;
    }
    unsafeAtomicAdd(&in_fea[d * DD + j], accF);    // hw global_atomic_add_f32
    unsafeAtomicAdd(&out_fea[s * DD + j], accR);
}

// One half-wave per node. cat = [in_fea | out_fea | prop] (96), lane j holds
// element j of each 32-segment; broadcasts via shuffle. Three 96x32 matvecs.
__global__ void gru_kernel(const float* __restrict__ W_r, const float* __restrict__ b_r,
                           const float* __restrict__ W_z, const float* __restrict__ b_z,
                           const float* __restrict__ W_t, const float* __restrict__ b_t,
                           const float* __restrict__ in_fea,
                           const float* __restrict__ out_fea,
                           float* __restrict__ prop) {
    int n = blockIdx.x * 8 + (threadIdx.x >> 5);   // 6250 * 8 = 50000 exact
    int lane = threadIdx.x & 63;
    int j = threadIdx.x & 31;
    int base = lane & 32;
    float a = in_fea[n * DD + j];
    float b = out_fea[n * DD + j];
    float p = prop[n * DD + j];

    float r_acc = b_r[j];
    float z_acc = b_z[j];
    float seg0 = a, seg1 = b, seg2 = p;
#pragma unroll
    for (int s = 0; s < 3; ++s) {
        float v = (s == 0) ? seg0 : (s == 1) ? seg1 : seg2;
#pragma unroll
        for (int m = 0; m < DD; ++m) {
            float c = __shfl(v, base + m);
            int row = s * DD + m;
            r_acc += c * W_r[row * DD + j];        // coalesced over j, cache-resident
            z_acc += c * W_z[row * DD + j];
        }
    }
    float r = 1.f / (1.f + __expf(-r_acc));
    float z = 1.f / (1.f + __expf(-z_acc));

    float t_acc = b_t[j];
    seg2 = r * p;                                   // cat2 = [in_fea | out_fea | r*prop]
#pragma unroll
    for (int s = 0; s < 3; ++s) {
        float v = (s == 0) ? seg0 : (s == 1) ? seg1 : seg2;
#pragma unroll
        for (int m = 0; m < DD; ++m) {
            float c = __shfl(v, base + m);
            t_acc += c * W_t[(s * DD + m) * DD + j];
        }
    }
    float hh = tanhf(t_acc);
    prop[n * DD + j] = (1.f - z) * p + z * hh;      // in-place: same-node only
}

__global__ void copy_out(const float* __restrict__ prop, float* __restrict__ out) {
    int idx = blockIdx.x * 256 + threadIdx.x;
    out[idx] = prop[idx];
}

extern "C" void kernel_launch(void* const* d_in, const int* in_sizes, int n_in,
                              void* d_out, int out_size, void* d_ws, size_t ws_size,
                              hipStream_t stream) {
    const int*   token  = (const int*)d_in[0];
    const int*   etype  = (const int*)d_in[1];
    const int*   src    = (const int*)d_in[2];
    const int*   dst    = (const int*)d_in[3];
    const float* emb    = (const float*)d_in[4];
    const float* W_edge = (const float*)d_in[5];
    const float* W_r    = (const float*)d_in[6];
    const float* b_r    = (const float*)d_in[7];
    const float* W_z    = (const float*)d_in[8];
    const float* b_z    = (const float*)d_in[9];
    const float* W_t    = (const float*)d_in[10];
    const float* b_t    = (const float*)d_in[11];
    float* out = (float*)d_out;

    float* prop    = (float*)d_ws;                 // 6.4 MB
    float* in_fea  = prop   + N_NODES * DD;        // 6.4 MB
    float* out_fea = in_fea + N_NODES * DD;        // 6.4 MB (total 19.2 MB)

    init_prop<<<(N_NODES * DD) / 256, 256, 0, stream>>>(token, emb, prop);
    for (int step = 0; step < STEPS; ++step) {
        hipMemsetAsync(in_fea,  0, (size_t)N_NODES * DD * sizeof(float), stream);
        hipMemsetAsync(out_fea, 0, (size_t)N_NODES * DD * sizeof(float), stream);
        edge_kernel<<<N_EDGES / 8, 256, 0, stream>>>(etype, src, dst, W_edge,
                                                     prop, in_fea, out_fea);
        gru_kernel<<<N_NODES / 8, 256, 0, stream>>>(
            W_r, b_r, W_z, b_z, W_t, b_t, in_fea, out_fea, prop);
    }
    copy_out<<<(N_NODES * DD) / 256, 256, 0, stream>>>(prop, out);
}

// Round 3
// 1954.569 us; speedup vs baseline: 1.3423x; 1.3423x over previous
//
#include <hip/hip_runtime.h>

#define N_NODES 50000
#define N_EDGES 100000
#define DD 32
#define STEPS 5

// prop[n, j] = emb[token[n], j]
__global__ void init_prop(const int* __restrict__ token,
                          const float* __restrict__ emb,
                          float* __restrict__ prop) {
    int idx = blockIdx.x * 256 + threadIdx.x;   // over N*D = 1.6M, exact grid
    int n = idx >> 5, j = idx & 31;
    prop[idx] = emb[token[n] * DD + j];
}

// One half-wave (32 lanes) per edge. Lane j computes output column j for both
// fwd (k=0) and rev (k=1) transforms, then scatter-adds via hw f32 atomics.
__global__ void edge_kernel(const int* __restrict__ etype,
                            const int* __restrict__ src,
                            const int* __restrict__ dst,
                            const float* __restrict__ W_edge,
                            const float* __restrict__ prop,
                            float* __restrict__ in_fea,
                            float* __restrict__ out_fea) {
    int e = blockIdx.x * 8 + (threadIdx.x >> 5);   // 12500 * 8 = 100000 exact
    int lane = threadIdx.x & 63;
    int j = threadIdx.x & 31;
    int base = lane & 32;                          // half-wave lane origin
    int s = src[e], d = dst[e], t = etype[e];
    float h = prop[s * DD + j];                    // lane j holds h_src[j]
    const float2* W2 = (const float2*)W_edge + (size_t)t * (DD * DD);
    float accF = 0.f, accR = 0.f;
#pragma unroll
    for (int i = 0; i < DD; ++i) {
        float hi = __shfl(h, base + i);            // broadcast h_src[i] in half-wave
        float2 w = W2[i * DD + j];                 // coalesced over j
        accF += hi * w.x;
        accR += hi * w.y;
    }
    unsafeAtomicAdd(&in_fea[d * DD + j], accF);
    unsafeAtomicAdd(&out_fea[s * DD + j], accR);
}

// One THREAD per node. Weights are node-independent => wave-uniform addresses
// => compiler emits s_load into SGPRs and v_fmac_f32 vdst, sgpr, vgpr.
// cat[96] fully in registers (float4 loads). Three unrolled matvec passes
// (r, z, t) to cap live VGPRs at ~200.
__global__ __launch_bounds__(64) void
gru_kernel(const float* __restrict__ W_r, const float* __restrict__ b_r,
           const float* __restrict__ W_z, const float* __restrict__ b_z,
           const float* __restrict__ W_t, const float* __restrict__ b_t,
           const float* __restrict__ in_fea,
           const float* __restrict__ out_fea,
           float* __restrict__ prop) {
    int n = blockIdx.x * 64 + threadIdx.x;
    if (n >= N_NODES) return;

    float cat[3 * DD];
    {
        const float4* a4 = (const float4*)(in_fea  + (size_t)n * DD);
        const float4* b4 = (const float4*)(out_fea + (size_t)n * DD);
        const float4* p4 = (const float4*)(prop    + (size_t)n * DD);
#pragma unroll
        for (int q = 0; q < 8; ++q) {
            float4 va = a4[q], vb = b4[q], vp = p4[q];
            cat[q * 4 + 0] = va.x; cat[q * 4 + 1] = va.y;
            cat[q * 4 + 2] = va.z; cat[q * 4 + 3] = va.w;
            cat[DD + q * 4 + 0] = vb.x; cat[DD + q * 4 + 1] = vb.y;
            cat[DD + q * 4 + 2] = vb.z; cat[DD + q * 4 + 3] = vb.w;
            cat[2 * DD + q * 4 + 0] = vp.x; cat[2 * DD + q * 4 + 1] = vp.y;
            cat[2 * DD + q * 4 + 2] = vp.z; cat[2 * DD + q * 4 + 3] = vp.w;
        }
    }

    // r = sigmoid(cat @ W_r + b_r)
    float r[DD];
#pragma unroll
    for (int j = 0; j < DD; ++j) r[j] = b_r[j];
#pragma unroll
    for (int m = 0; m < 3 * DD; ++m) {
        float c = cat[m];
#pragma unroll
        for (int j = 0; j < DD; ++j) r[j] += c * W_r[m * DD + j];
    }
#pragma unroll
    for (int j = 0; j < DD; ++j) r[j] = 1.f / (1.f + __expf(-r[j]));

    // z = sigmoid(cat @ W_z + b_z)
    float z[DD];
#pragma unroll
    for (int j = 0; j < DD; ++j) z[j] = b_z[j];
#pragma unroll
    for (int m = 0; m < 3 * DD; ++m) {
        float c = cat[m];
#pragma unroll
        for (int j = 0; j < DD; ++j) z[j] += c * W_z[m * DD + j];
    }
#pragma unroll
    for (int j = 0; j < DD; ++j) z[j] = 1.f / (1.f + __expf(-z[j]));

    // r := r * p  (third segment of cat2); original p stays in cat[64..95]
#pragma unroll
    for (int j = 0; j < DD; ++j) r[j] *= cat[2 * DD + j];

    // t = tanh(cat2 @ W_t + b_t)
    float t[DD];
#pragma unroll
    for (int j = 0; j < DD; ++j) t[j] = b_t[j];
#pragma unroll
    for (int m = 0; m < 2 * DD; ++m) {
        float c = cat[m];
#pragma unroll
        for (int j = 0; j < DD; ++j) t[j] += c * W_t[m * DD + j];
    }
#pragma unroll
    for (int m = 0; m < DD; ++m) {
        float c = r[m];
#pragma unroll
        for (int j = 0; j < DD; ++j) t[j] += c * W_t[(2 * DD + m) * DD + j];
    }

    // prop = (1-z)*p + z*tanh(t)
    float4* o4 = (float4*)(prop + (size_t)n * DD);
#pragma unroll
    for (int q = 0; q < 8; ++q) {
        float4 o;
        float h0 = tanhf(t[q * 4 + 0]), h1 = tanhf(t[q * 4 + 1]);
        float h2 = tanhf(t[q * 4 + 2]), h3 = tanhf(t[q * 4 + 3]);
        o.x = (1.f - z[q * 4 + 0]) * cat[2 * DD + q * 4 + 0] + z[q * 4 + 0] * h0;
        o.y = (1.f - z[q * 4 + 1]) * cat[2 * DD + q * 4 + 1] + z[q * 4 + 1] * h1;
        o.z = (1.f - z[q * 4 + 2]) * cat[2 * DD + q * 4 + 2] + z[q * 4 + 2] * h2;
        o.w = (1.f - z[q * 4 + 3]) * cat[2 * DD + q * 4 + 3] + z[q * 4 + 3] * h3;
        o4[q] = o;
    }
}

__global__ void copy_out(const float* __restrict__ prop, float* __restrict__ out) {
    int idx = blockIdx.x * 256 + threadIdx.x;
    out[idx] = prop[idx];
}

extern "C" void kernel_launch(void* const* d_in, const int* in_sizes, int n_in,
                              void* d_out, int out_size, void* d_ws, size_t ws_size,
                              hipStream_t stream) {
    const int*   token  = (const int*)d_in[0];
    const int*   etype  = (const int*)d_in[1];
    const int*   src    = (const int*)d_in[2];
    const int*   dst    = (const int*)d_in[3];
    const float* emb    = (const float*)d_in[4];
    const float* W_edge = (const float*)d_in[5];
    const float* W_r    = (const float*)d_in[6];
    const float* b_r    = (const float*)d_in[7];
    const float* W_z    = (const float*)d_in[8];
    const float* b_z    = (const float*)d_in[9];
    const float* W_t    = (const float*)d_in[10];
    const float* b_t    = (const float*)d_in[11];
    float* out = (float*)d_out;

    float* prop    = (float*)d_ws;                 // 6.4 MB
    float* in_fea  = prop   + N_NODES * DD;        // 6.4 MB
    float* out_fea = in_fea + N_NODES * DD;        // 6.4 MB (total 19.2 MB)

    init_prop<<<(N_NODES * DD) / 256, 256, 0, stream>>>(token, emb, prop);
    for (int step = 0; step < STEPS; ++step) {
        hipMemsetAsync(in_fea,  0, (size_t)N_NODES * DD * sizeof(float), stream);
        hipMemsetAsync(out_fea, 0, (size_t)N_NODES * DD * sizeof(float), stream);
        edge_kernel<<<N_EDGES / 8, 256, 0, stream>>>(etype, src, dst, W_edge,
                                                     prop, in_fea, out_fea);
        gru_kernel<<<(N_NODES + 63) / 64, 64, 0, stream>>>(
            W_r, b_r, W_z, b_z, W_t, b_t, in_fea, out_fea, prop);
    }
    copy_out<<<(N_NODES * DD) / 256, 256, 0, stream>>>(prop, out);
}

// Round 4
// 508.875 us; speedup vs baseline: 5.1556x; 3.8410x over previous
//
#include <hip/hip_runtime.h>

#define N_NODES 50000
#define N_EDGES 100000
#define DD 32
#define STEPS 5

#define NPT 4            // nodes per thread
#define NPB 128          // nodes per block (32 ng * NPT)
#define CAT_STRIDE 100   // floats per cat row (96 + 4 pad) -> conflict-free b128

// prop[n, j] = emb[token[n], j]
__global__ void init_prop(const int* __restrict__ token,
                          const float* __restrict__ emb,
                          float* __restrict__ prop) {
    int idx = blockIdx.x * 256 + threadIdx.x;   // over N*D = 1.6M, exact grid
    int n = idx >> 5, j = idx & 31;
    prop[idx] = emb[token[n] * DD + j];
}

// One half-wave (32 lanes) per edge; hw f32 atomics for segment sums.
__global__ void edge_kernel(const int* __restrict__ etype,
                            const int* __restrict__ src,
                            const int* __restrict__ dst,
                            const float* __restrict__ W_edge,
                            const float* __restrict__ prop,
                            float* __restrict__ in_fea,
                            float* __restrict__ out_fea) {
    int e = blockIdx.x * 8 + (threadIdx.x >> 5);   // 12500 * 8 = 100000 exact
    int lane = threadIdx.x & 63;
    int j = threadIdx.x & 31;
    int base = lane & 32;
    int s = src[e], d = dst[e], t = etype[e];
    float h = prop[s * DD + j];
    const float2* W2 = (const float2*)W_edge + (size_t)t * (DD * DD);
    float accF = 0.f, accR = 0.f;
#pragma unroll
    for (int i = 0; i < DD; ++i) {
        float hi = __shfl(h, base + i);
        float2 w = W2[i * DD + j];
        accF += hi * w.x;
        accR += hi * w.y;
    }
    unsafeAtomicAdd(&in_fea[d * DD + j], accF);
    unsafeAtomicAdd(&out_fea[s * DD + j], accR);
}

__device__ __forceinline__ void fma4(float (&acc)[4], float c, const float4& w) {
    acc[0] = fmaf(c, w.x, acc[0]);
    acc[1] = fmaf(c, w.y, acc[1]);
    acc[2] = fmaf(c, w.z, acc[2]);
    acc[3] = fmaf(c, w.w, acc[3]);
}
__device__ __forceinline__ float sigm(float x) {
    return 1.f / (1.f + __expf(-x));
}
__device__ __forceinline__ float fast_tanh(float x) {
    x = fminf(fmaxf(x, -15.f), 15.f);
    float e = __expf(2.f * x);
    return (e - 1.f) / (e + 1.f);
}

// Block = 256 threads = 128 nodes. cat[node][0..95] = [in|out|prop] in LDS
// (stride 100 -> b128 reads of 4 m's, conflict-free across ng lanes).
// Thread = 4 nodes x 4 cols: weights via coalesced global dwordx4 (L1-hot),
// c via ds_read_b128, 128 fmac per 4-row group -> VALU-bound.
__global__ __launch_bounds__(256) void
gru_kernel(const float* __restrict__ W_r, const float* __restrict__ b_r,
           const float* __restrict__ W_z, const float* __restrict__ b_z,
           const float* __restrict__ W_t, const float* __restrict__ b_t,
           const float* __restrict__ in_fea,
           const float* __restrict__ out_fea,
           float* __restrict__ prop) {
    __shared__ float cat[NPB * CAT_STRIDE];           // 51.2 KB
    float4* cat4 = (float4*)cat;                      // row stride 25 float4
    const int tid = threadIdx.x;
    const int n0 = blockIdx.x * NPB;
    const int jq = tid & 7;                           // col quad: cols jq*4..jq*4+3
    const int ng = tid >> 3;                          // 0..31; nodes ng + 32k

    // ---- stage in/out/prop -> cat ----
    {
        const float4* a4 = (const float4*)(in_fea  + (size_t)n0 * DD);
        const float4* b4 = (const float4*)(out_fea + (size_t)n0 * DD);
        const float4* p4 = (const float4*)(prop    + (size_t)n0 * DD);
        const float4 zz = {0.f, 0.f, 0.f, 0.f};
#pragma unroll
        for (int q = 0; q < 4; ++q) {
            int f = q * 256 + tid;                    // float4 index, [0,1024)
            int node = f >> 3;                        // 8 float4 per 32-col row
            int c4 = f & 7;
            bool ok = (n0 + node) < N_NODES;
            cat4[node * 25 + c4]      = ok ? a4[f] : zz;
            cat4[node * 25 + 8 + c4]  = ok ? b4[f] : zz;
            cat4[node * 25 + 16 + c4] = ok ? p4[f] : zz;
        }
    }
    __syncthreads();

    // ---- phase A: r,z ----
    float r_[NPT][4], z_[NPT][4];
    {
        float4 br = ((const float4*)b_r)[jq];
        float4 bz = ((const float4*)b_z)[jq];
#pragma unroll
        for (int k = 0; k < NPT; ++k) {
            r_[k][0] = br.x; r_[k][1] = br.y; r_[k][2] = br.z; r_[k][3] = br.w;
            z_[k][0] = bz.x; z_[k][1] = bz.y; z_[k][2] = bz.z; z_[k][3] = bz.w;
        }
    }
#pragma unroll 1
    for (int g = 0; g < 24; ++g) {                    // rows m0..m0+3
        int m0 = g * 4;
        float4 wr[4], wz[4];
#pragma unroll
        for (int i = 0; i < 4; ++i) {
            wr[i] = ((const float4*)(W_r + (m0 + i) * DD))[jq];
            wz[i] = ((const float4*)(W_z + (m0 + i) * DD))[jq];
        }
#pragma unroll
        for (int k = 0; k < NPT; ++k) {
            float4 c = cat4[(ng + 32 * k) * 25 + g];
            fma4(r_[k], c.x, wr[0]); fma4(r_[k], c.y, wr[1]);
            fma4(r_[k], c.z, wr[2]); fma4(r_[k], c.w, wr[3]);
            fma4(z_[k], c.x, wz[0]); fma4(z_[k], c.y, wz[1]);
            fma4(z_[k], c.z, wz[2]); fma4(z_[k], c.w, wz[3]);
        }
    }

    // sigmoid; read own p; then overwrite LDS rows 64..95 with r*p
    float p_[NPT][4];
#pragma unroll
    for (int k = 0; k < NPT; ++k) {
        float4 p = cat4[(ng + 32 * k) * 25 + 16 + jq];
        p_[k][0] = p.x; p_[k][1] = p.y; p_[k][2] = p.z; p_[k][3] = p.w;
#pragma unroll
        for (int j = 0; j < 4; ++j) {
            r_[k][j] = sigm(r_[k][j]) * p_[k][j];     // r := r*p
            z_[k][j] = sigm(z_[k][j]);
        }
    }
    __syncthreads();                                  // all phase-A reads done
#pragma unroll
    for (int k = 0; k < NPT; ++k) {
        float4 rp = {r_[k][0], r_[k][1], r_[k][2], r_[k][3]};
        cat4[(ng + 32 * k) * 25 + 16 + jq] = rp;
    }
    __syncthreads();                                  // rp visible to all

    // ---- phase B: t ----
    float t_[NPT][4];
    {
        float4 bt = ((const float4*)b_t)[jq];
#pragma unroll
        for (int k = 0; k < NPT; ++k) {
            t_[k][0] = bt.x; t_[k][1] = bt.y; t_[k][2] = bt.z; t_[k][3] = bt.w;
        }
    }
#pragma unroll 1
    for (int g = 0; g < 24; ++g) {
        int m0 = g * 4;
        float4 wt[4];
#pragma unroll
        for (int i = 0; i < 4; ++i)
            wt[i] = ((const float4*)(W_t + (m0 + i) * DD))[jq];
#pragma unroll
        for (int k = 0; k < NPT; ++k) {
            float4 c = cat4[(ng + 32 * k) * 25 + g];
            fma4(t_[k], c.x, wt[0]); fma4(t_[k], c.y, wt[1]);
            fma4(t_[k], c.z, wt[2]); fma4(t_[k], c.w, wt[3]);
        }
    }

    // ---- update: prop = p + z*(tanh(t) - p) ----
#pragma unroll
    for (int k = 0; k < NPT; ++k) {
        int node = n0 + ng + 32 * k;
        if (node < N_NODES) {
            float4 o;
            o.x = fmaf(z_[k][0], fast_tanh(t_[k][0]) - p_[k][0], p_[k][0]);
            o.y = fmaf(z_[k][1], fast_tanh(t_[k][1]) - p_[k][1], p_[k][1]);
            o.z = fmaf(z_[k][2], fast_tanh(t_[k][2]) - p_[k][2], p_[k][2]);
            o.w = fmaf(z_[k][3], fast_tanh(t_[k][3]) - p_[k][3], p_[k][3]);
            ((float4*)(prop + (size_t)node * DD))[jq] = o;
        }
    }
}

__global__ void copy_out(const float* __restrict__ prop, float* __restrict__ out) {
    int idx = blockIdx.x * 256 + threadIdx.x;
    out[idx] = prop[idx];
}

extern "C" void kernel_launch(void* const* d_in, const int* in_sizes, int n_in,
                              void* d_out, int out_size, void* d_ws, size_t ws_size,
                              hipStream_t stream) {
    const int*   token  = (const int*)d_in[0];
    const int*   etype  = (const int*)d_in[1];
    const int*   src    = (const int*)d_in[2];
    const int*   dst    = (const int*)d_in[3];
    const float* emb    = (const float*)d_in[4];
    const float* W_edge = (const float*)d_in[5];
    const float* W_r    = (const float*)d_in[6];
    const float* b_r    = (const float*)d_in[7];
    const float* W_z    = (const float*)d_in[8];
    const float* b_z    = (const float*)d_in[9];
    const float* W_t    = (const float*)d_in[10];
    const float* b_t    = (const float*)d_in[11];
    float* out = (float*)d_out;

    float* prop    = (float*)d_ws;                 // 6.4 MB
    float* in_fea  = prop   + N_NODES * DD;        // 6.4 MB
    float* out_fea = in_fea + N_NODES * DD;        // 6.4 MB

    init_prop<<<(N_NODES * DD) / 256, 256, 0, stream>>>(token, emb, prop);
    for (int step = 0; step < STEPS; ++step) {
        hipMemsetAsync(in_fea,  0, (size_t)N_NODES * DD * sizeof(float), stream);
        hipMemsetAsync(out_fea, 0, (size_t)N_NODES * DD * sizeof(float), stream);
        edge_kernel<<<N_EDGES / 8, 256, 0, stream>>>(etype, src, dst, W_edge,
                                                     prop, in_fea, out_fea);
        gru_kernel<<<(N_NODES + NPB - 1) / NPB, 256, 0, stream>>>(
            W_r, b_r, W_z, b_z, W_t, b_t, in_fea, out_fea, prop);
    }
    copy_out<<<(N_NODES * DD) / 256, 256, 0, stream>>>(prop, out);
}

// Round 5
// 496.310 us; speedup vs baseline: 5.2861x; 1.0253x over previous
//
#include <hip/hip_runtime.h>

#define N_NODES 50000
#define N_EDGES 100000
#define DD 32
#define STEPS 5

#define NPT 4            // nodes per thread (gru)
#define NPB 128          // nodes per block (gru)
#define CAT_STRIDE 100   // floats per cat row (96 + 4 pad)

// prop[n,j] = emb[token[n],j]; also zero-init the two accumulators (step 0).
__global__ void init_prop(const int* __restrict__ token,
                          const float* __restrict__ emb,
                          float* __restrict__ prop,
                          float* __restrict__ in_fea,
                          float* __restrict__ out_fea) {
    int idx = blockIdx.x * 256 + threadIdx.x;   // over N*D = 1.6M, exact grid
    int n = idx >> 5, j = idx & 31;
    prop[idx] = emb[token[n] * DD + j];
    in_fea[idx] = 0.f;
    out_fea[idx] = 0.f;
}

// Half-wave (32 lanes) per 4 edges: 4 independent gathers + 8 independent fma
// chains in flight per half-wave to hide gather/atomic latency.
__global__ void edge_kernel(const int* __restrict__ etype,
                            const int* __restrict__ src,
                            const int* __restrict__ dst,
                            const float* __restrict__ W_edge,
                            const float* __restrict__ prop,
                            float* __restrict__ in_fea,
                            float* __restrict__ out_fea) {
    int hw = threadIdx.x >> 5;                     // half-wave 0..7 in block
    int e0 = blockIdx.x * 32 + hw * 4;             // 3125 * 32 = 100000 exact
    int lane = threadIdx.x & 63;
    int j = threadIdx.x & 31;
    int base = lane & 32;
    int s[4], d[4], t[4];
    float h[4];
#pragma unroll
    for (int k = 0; k < 4; ++k) {
        s[k] = src[e0 + k]; d[k] = dst[e0 + k]; t[k] = etype[e0 + k];
    }
#pragma unroll
    for (int k = 0; k < 4; ++k) h[k] = prop[s[k] * DD + j];  // 4 gathers in flight
    const float2* W2[4];
#pragma unroll
    for (int k = 0; k < 4; ++k)
        W2[k] = (const float2*)W_edge + (size_t)t[k] * (DD * DD);
    float aF[4] = {0.f, 0.f, 0.f, 0.f}, aR[4] = {0.f, 0.f, 0.f, 0.f};
#pragma unroll
    for (int i = 0; i < DD; ++i) {
#pragma unroll
        for (int k = 0; k < 4; ++k) {
            float hi = __shfl(h[k], base + i);     // broadcast h_k[i] in half-wave
            float2 w = W2[k][i * DD + j];          // coalesced over j, L1-hot
            aF[k] = fmaf(hi, w.x, aF[k]);
            aR[k] = fmaf(hi, w.y, aR[k]);
        }
    }
#pragma unroll
    for (int k = 0; k < 4; ++k) {
        unsafeAtomicAdd(&in_fea[d[k] * DD + j], aF[k]);
        unsafeAtomicAdd(&out_fea[s[k] * DD + j], aR[k]);
    }
}

__device__ __forceinline__ void fma4(float (&acc)[4], float c, const float4& w) {
    acc[0] = fmaf(c, w.x, acc[0]);
    acc[1] = fmaf(c, w.y, acc[1]);
    acc[2] = fmaf(c, w.z, acc[2]);
    acc[3] = fmaf(c, w.w, acc[3]);
}
__device__ __forceinline__ float sigm(float x) {
    return 1.f / (1.f + __expf(-x));
}
__device__ __forceinline__ float fast_tanh(float x) {
    x = fminf(fmaxf(x, -15.f), 15.f);
    float e = __expf(2.f * x);
    return (e - 1.f) / (e + 1.f);
}

// Block = 256 threads = 128 nodes. Stages cat=[in|out|prop] to LDS, zeroes
// in/out_fea in-place for the next step (this block is their last reader),
// runs r/z then t matvecs, updates prop; on the final step also writes out2.
__global__ __launch_bounds__(256) void
gru_kernel(const float* __restrict__ W_r, const float* __restrict__ b_r,
           const float* __restrict__ W_z, const float* __restrict__ b_z,
           const float* __restrict__ W_t, const float* __restrict__ b_t,
           float* __restrict__ in_fea,
           float* __restrict__ out_fea,
           float* __restrict__ prop,
           float* __restrict__ out2) {
    __shared__ float cat[NPB * CAT_STRIDE];           // 51.2 KB
    float4* cat4 = (float4*)cat;                      // row stride 25 float4
    const int tid = threadIdx.x;
    const int n0 = blockIdx.x * NPB;
    const int jq = tid & 7;
    const int ng = tid >> 3;

    // ---- stage in/out/prop -> LDS, then zero in/out_fea for next step ----
    {
        const float4* a4 = (const float4*)(in_fea  + (size_t)n0 * DD);
        const float4* b4 = (const float4*)(out_fea + (size_t)n0 * DD);
        const float4* p4 = (const float4*)(prop    + (size_t)n0 * DD);
        const float4 zz = {0.f, 0.f, 0.f, 0.f};
#pragma unroll
        for (int q = 0; q < 4; ++q) {
            int f = q * 256 + tid;                    // float4 index in block range
            int node = f >> 3;
            int c4 = f & 7;
            bool ok = (n0 + node) < N_NODES;
            float4 va = ok ? a4[f] : zz;
            float4 vb = ok ? b4[f] : zz;
            float4 vp = ok ? p4[f] : zz;
            cat4[node * 25 + c4]      = va;
            cat4[node * 25 + 8 + c4]  = vb;
            cat4[node * 25 + 16 + c4] = vp;
            if (ok) {                                 // same thread, same addr: safe
                ((float4*)(in_fea  + (size_t)n0 * DD))[f] = zz;
                ((float4*)(out_fea + (size_t)n0 * DD))[f] = zz;
            }
        }
    }
    __syncthreads();

    // ---- phase A: r,z ----
    float r_[NPT][4], z_[NPT][4];
    {
        float4 br = ((const float4*)b_r)[jq];
        float4 bz = ((const float4*)b_z)[jq];
#pragma unroll
        for (int k = 0; k < NPT; ++k) {
            r_[k][0] = br.x; r_[k][1] = br.y; r_[k][2] = br.z; r_[k][3] = br.w;
            z_[k][0] = bz.x; z_[k][1] = bz.y; z_[k][2] = bz.z; z_[k][3] = bz.w;
        }
    }
#pragma unroll 1
    for (int g = 0; g < 24; ++g) {
        int m0 = g * 4;
        float4 wr[4], wz[4];
#pragma unroll
        for (int i = 0; i < 4; ++i) {
            wr[i] = ((const float4*)(W_r + (m0 + i) * DD))[jq];
            wz[i] = ((const float4*)(W_z + (m0 + i) * DD))[jq];
        }
#pragma unroll
        for (int k = 0; k < NPT; ++k) {
            float4 c = cat4[(ng + 32 * k) * 25 + g];
            fma4(r_[k], c.x, wr[0]); fma4(r_[k], c.y, wr[1]);
            fma4(r_[k], c.z, wr[2]); fma4(r_[k], c.w, wr[3]);
            fma4(z_[k], c.x, wz[0]); fma4(z_[k], c.y, wz[1]);
            fma4(z_[k], c.z, wz[2]); fma4(z_[k], c.w, wz[3]);
        }
    }

    float p_[NPT][4];
#pragma unroll
    for (int k = 0; k < NPT; ++k) {
        float4 p = cat4[(ng + 32 * k) * 25 + 16 + jq];
        p_[k][0] = p.x; p_[k][1] = p.y; p_[k][2] = p.z; p_[k][3] = p.w;
#pragma unroll
        for (int j = 0; j < 4; ++j) {
            r_[k][j] = sigm(r_[k][j]) * p_[k][j];     // r := r*p
            z_[k][j] = sigm(z_[k][j]);
        }
    }
    __syncthreads();
#pragma unroll
    for (int k = 0; k < NPT; ++k) {
        float4 rp = {r_[k][0], r_[k][1], r_[k][2], r_[k][3]};
        cat4[(ng + 32 * k) * 25 + 16 + jq] = rp;
    }
    __syncthreads();

    // ---- phase B: t ----
    float t_[NPT][4];
    {
        float4 bt = ((const float4*)b_t)[jq];
#pragma unroll
        for (int k = 0; k < NPT; ++k) {
            t_[k][0] = bt.x; t_[k][1] = bt.y; t_[k][2] = bt.z; t_[k][3] = bt.w;
        }
    }
#pragma unroll 1
    for (int g = 0; g < 24; ++g) {
        int m0 = g * 4;
        float4 wt[4];
#pragma unroll
        for (int i = 0; i < 4; ++i)
            wt[i] = ((const float4*)(W_t + (m0 + i) * DD))[jq];
#pragma unroll
        for (int k = 0; k < NPT; ++k) {
            float4 c = cat4[(ng + 32 * k) * 25 + g];
            fma4(t_[k], c.x, wt[0]); fma4(t_[k], c.y, wt[1]);
            fma4(t_[k], c.z, wt[2]); fma4(t_[k], c.w, wt[3]);
        }
    }

    // ---- update: prop = p + z*(tanh(t) - p); final step also writes out2 ----
#pragma unroll
    for (int k = 0; k < NPT; ++k) {
        int node = n0 + ng + 32 * k;
        if (node < N_NODES) {
            float4 o;
            o.x = fmaf(z_[k][0], fast_tanh(t_[k][0]) - p_[k][0], p_[k][0]);
            o.y = fmaf(z_[k][1], fast_tanh(t_[k][1]) - p_[k][1], p_[k][1]);
            o.z = fmaf(z_[k][2], fast_tanh(t_[k][2]) - p_[k][2], p_[k][2]);
            o.w = fmaf(z_[k][3], fast_tanh(t_[k][3]) - p_[k][3], p_[k][3]);
            ((float4*)(prop + (size_t)node * DD))[jq] = o;
            if (out2) ((float4*)(out2 + (size_t)node * DD))[jq] = o;
        }
    }
}

extern "C" void kernel_launch(void* const* d_in, const int* in_sizes, int n_in,
                              void* d_out, int out_size, void* d_ws, size_t ws_size,
                              hipStream_t stream) {
    const int*   token  = (const int*)d_in[0];
    const int*   etype  = (const int*)d_in[1];
    const int*   src    = (const int*)d_in[2];
    const int*   dst    = (const int*)d_in[3];
    const float* emb    = (const float*)d_in[4];
    const float* W_edge = (const float*)d_in[5];
    const float* W_r    = (const float*)d_in[6];
    const float* b_r    = (const float*)d_in[7];
    const float* W_z    = (const float*)d_in[8];
    const float* b_z    = (const float*)d_in[9];
    const float* W_t    = (const float*)d_in[10];
    const float* b_t    = (const float*)d_in[11];
    float* out = (float*)d_out;

    float* prop    = (float*)d_ws;                 // 6.4 MB
    float* in_fea  = prop   + N_NODES * DD;        // 6.4 MB
    float* out_fea = in_fea + N_NODES * DD;        // 6.4 MB

    init_prop<<<(N_NODES * DD) / 256, 256, 0, stream>>>(token, emb, prop,
                                                        in_fea, out_fea);
    for (int step = 0; step < STEPS; ++step) {
        edge_kernel<<<N_EDGES / 32, 256, 0, stream>>>(etype, src, dst, W_edge,
                                                      prop, in_fea, out_fea);
        gru_kernel<<<(N_NODES + NPB - 1) / NPB, 256, 0, stream>>>(
            W_r, b_r, W_z, b_z, W_t, b_t, in_fea, out_fea, prop,
            (step == STEPS - 1) ? out : nullptr);
    }
}